// Round 11
// baseline (358.936 us; speedup 1.0000x reference)
//
#include <hip/hip_runtime.h>

#define EDGES 400000
#define NN 25000
#define NCH 288
#define EPB 32          // fused-fallback tile
#define EPA 64          // k_mlp tile (4 waves x 16 edges)
#define NBIN_PAD 25024

#define W1FRAG 16384   // 2 k2 * 16 nt * 64 lane * 8 el
#define W2FRAG 24576   // 8 k8 * 6 nt * 64 lane * 8 el

typedef float f32x4 __attribute__((ext_vector_type(4)));
typedef short short8 __attribute__((ext_vector_type(8)));

__device__ __forceinline__ unsigned short f2bf(float x) {          // RNE
    unsigned u = __float_as_uint(x);
    unsigned r = (u + 0x7fffu + ((u >> 16) & 1u)) >> 16;
    return (unsigned short)r;
}
__device__ __forceinline__ unsigned short f2bf_t(float x) {        // truncate
    return (unsigned short)(__float_as_uint(x) >> 16);
}
__device__ __forceinline__ float bf2f(unsigned short h) {
    return __uint_as_float(((unsigned)h) << 16);
}
__device__ __forceinline__ unsigned cvtpk(float a, float b) {      // 2xf32 -> 2xbf16 RNE
    unsigned r;
    asm("v_cvt_pk_bf16_f32 %0, %1, %2" : "=v"(r) : "v"(a), "v"(b));
    return r;
}
__device__ __forceinline__ float lowf(unsigned u)  { return __uint_as_float(u << 16); }
__device__ __forceinline__ float highf(unsigned u) { return __uint_as_float(u & 0xffff0000u); }
__device__ __forceinline__ short8 mk8(unsigned a, unsigned b, unsigned c, unsigned d) {
    union { unsigned u[4]; short8 s; } x;
    x.u[0] = a; x.u[1] = b; x.u[2] = c; x.u[3] = d;
    return x.s;
}

// ---------------- weight -> fragment-order bf16 hi/lo precompute ----------------
// region 0: W1 frags, classic n = nt*16 + p           (used by fused fallback)
// region 1: W2 frags (shared)
// region 2: W1 frags, sigma-permuted n                (used by barrier-free k_mlp)
__global__ void k_wfrag(const float* __restrict__ W1, const float* __restrict__ W2,
                        unsigned short* __restrict__ w1h, unsigned short* __restrict__ w1l,
                        unsigned short* __restrict__ w2h, unsigned short* __restrict__ w2l,
                        unsigned short* __restrict__ w1hs, unsigned short* __restrict__ w1ls) {
    int i = blockIdx.x * 256 + threadIdx.x;
    if (i < W1FRAG) {
        int j = i & 7, l = (i >> 3) & 63, nt = (i >> 9) & 15, k2 = (i >> 13) & 1;
        int n = nt * 16 + (l & 15), k = k2 * 32 + ((l >> 4) * 8) + j;
        float v = W1[k * 256 + n] * 0.125f;              // fold 1/sqrt(64)
        unsigned short hb = f2bf(v);
        w1h[i] = hb; w1l[i] = f2bf_t(v - bf2f(hb));
    } else if (i < W1FRAG + W2FRAG) {
        int i2 = i - W1FRAG;
        int j = i2 & 7, l = (i2 >> 3) & 63, r = i2 >> 9;  // r in [0,48)
        int nt = r % 6, k8 = r / 6;
        int n = nt * 16 + (l & 15), k = k8 * 32 + ((l >> 4) * 8) + j;
        float v = W2[k * 96 + n] * 0.015625f;            // fold 1/sqrt(256)*1/sqrt(16)
        unsigned short hb = f2bf(v);
        w2h[i2] = hb; w2l[i2] = f2bf_t(v - bf2f(hb));
    } else if (i < 2 * W1FRAG + W2FRAG) {
        int i3 = i - (W1FRAG + W2FRAG);
        int j = i3 & 7, l = (i3 >> 3) & 63, nt = (i3 >> 9) & 15, k2 = (i3 >> 13) & 1;
        int p = l & 15;
        // sigma(nt,p): layer-1 D position (nt, p=g*4+r) holds hidden unit n such that
        // layer-2's A-frag slot (ks=nt>>1, g=p>>2, j=(nt&1)*4+(p&3)) = h[n] lane-locally
        int n = ((nt >> 1) * 32) + ((p >> 2) * 8) + ((nt & 1) * 4) + (p & 3);
        int k = k2 * 32 + ((l >> 4) * 8) + j;
        float v = W1[k * 256 + n] * 0.125f;
        unsigned short hb = f2bf(v);
        w1hs[i3] = hb; w1ls[i3] = f2bf_t(v - bf2f(hb));
    }
}

// ---------------- counting sort (dst-ordered edges) ----------------
__global__ void k_hist(const int* __restrict__ edst, unsigned* __restrict__ cnt) {
    int i = blockIdx.x * 256 + threadIdx.x;
    if (i < EDGES) atomicAdd(&cnt[edst[i]], 1u);
}

__global__ __launch_bounds__(1024) void k_scan(const unsigned* __restrict__ cnt,
                                               unsigned* __restrict__ cur,
                                               unsigned* __restrict__ rowp) {
    __shared__ unsigned s_wt[16];
    __shared__ unsigned s_carry;
    const int t = threadIdx.x, lane = t & 63, wid = t >> 6;
    if (t == 0) s_carry = 0u;
    __syncthreads();
    for (int base = 0; base < NN; base += 1024) {
        int i = base + t;
        unsigned v = (i < NN) ? cnt[i] : 0u;
        unsigned incl = v;
        #pragma unroll
        for (int d = 1; d < 64; d <<= 1) {
            unsigned u = __shfl_up(incl, d);
            if (lane >= d) incl += u;
        }
        if (lane == 63) s_wt[wid] = incl;
        __syncthreads();
        if (wid == 0 && lane < 16) {
            unsigned wincl = s_wt[lane];
            #pragma unroll
            for (int d = 1; d < 16; d <<= 1) {
                unsigned u = __shfl_up(wincl, d);
                if (lane >= d) wincl += u;
            }
            s_wt[lane] = wincl;
        }
        __syncthreads();
        unsigned waveoff = (wid > 0) ? s_wt[wid - 1] : 0u;
        unsigned carry = s_carry;
        if (i < NN) {
            unsigned ex = carry + waveoff + incl - v;
            cur[i] = ex;
            rowp[i] = ex;
        }
        __syncthreads();
        if (t == 1023) s_carry = carry + s_wt[15];
        __syncthreads();
    }
    if (t == 0) rowp[NN] = EDGES;
}

__global__ void k_perm(const int* __restrict__ edst, unsigned* __restrict__ cur,
                       unsigned* __restrict__ perm) {
    int i = blockIdx.x * 256 + threadIdx.x;
    if (i < EDGES) {
        unsigned p = atomicAdd(&cur[edst[i]], 1u);
        perm[p] = (unsigned)i;
    }
}

__global__ void k_perm2(const int* __restrict__ edst, const int* __restrict__ esrc,
                        unsigned* __restrict__ cur, unsigned* __restrict__ perm,
                        int* __restrict__ ssrc) {
    int i = blockIdx.x * 256 + threadIdx.x;
    if (i < EDGES) {
        int d = edst[i];
        unsigned p = atomicAdd(&cur[d], 1u);
        perm[p] = (unsigned)i;
        ssrc[p] = esrc[i];
    }
}

// ---------------- kernel A: barrier-free, LDS-free MLP (wave = 16 edges) ----------------
__global__ __launch_bounds__(256) void k_mlp(
    const float* __restrict__ etype,
    const unsigned short* __restrict__ w1hs, const unsigned short* __restrict__ w1ls,
    const unsigned short* __restrict__ w2h, const unsigned short* __restrict__ w2l,
    const unsigned* __restrict__ perm,
    float* __restrict__ w_sorted)
{
    const int t = threadIdx.x;
    const int lane = t & 63, w = t >> 6;
    const int g = lane >> 4, e15 = lane & 15;
    const size_t slot0 = (size_t)blockIdx.x * EPA + (size_t)w * 16;   // wave's 16 slots

    const int eidx = (int)perm[slot0 + e15];

    // ---- etype B-fragments -> registers (hi/lo), loaded once, reused 16x ----
    short8 etH[2], etL[2];
    #pragma unroll
    for (int k2 = 0; k2 < 2; ++k2) {
        const float* rp = etype + (size_t)eidx * 64 + k2 * 32 + g * 8;
        float4 v0 = *(const float4*)rp;
        float4 v1 = *(const float4*)(rp + 4);
        unsigned h0 = cvtpk(v0.x, v0.y), h1 = cvtpk(v0.z, v0.w);
        unsigned h2 = cvtpk(v1.x, v1.y), h3 = cvtpk(v1.z, v1.w);
        float l0 = v0.x - lowf(h0), l1 = v0.y - highf(h0);
        float l2 = v0.z - lowf(h1), l3 = v0.w - highf(h1);
        float l4 = v1.x - lowf(h2), l5 = v1.y - highf(h2);
        float l6 = v1.z - lowf(h3), l7 = v1.w - highf(h3);
        etH[k2] = mk8(h0, h1, h2, h3);
        etL[k2] = mk8(cvtpk(l0, l1), cvtpk(l2, l3), cvtpk(l4, l5), cvtpk(l6, l7));
    }

    // layer-2 accumulators: D[e][c]; lane holds rows e = g*4+r, col c = nt*16 + e15
    f32x4 acc2[6];
    #pragma unroll
    for (int n = 0; n < 6; ++n)
        #pragma unroll
        for (int r = 0; r < 4; ++r) acc2[n][r] = 0.f;

    for (int ks = 0; ks < 8; ++ks) {
        // ---- layer 1 for n-tiles 2ks, 2ks+1 (sigma-permuted W1) ----
        f32x4 hsi[2];
        #pragma unroll
        for (int half = 0; half < 2; ++half) {
            int nt = 2 * ks + half;
            f32x4 a;
            #pragma unroll
            for (int r = 0; r < 4; ++r) a[r] = 0.f;
            #pragma unroll
            for (int k2 = 0; k2 < 2; ++k2) {
                int idx = ((k2 * 16 + nt) * 64 + lane) * 8;
                short8 wah = *(const short8*)(w1hs + idx);
                short8 wal = *(const short8*)(w1ls + idx);
                a = __builtin_amdgcn_mfma_f32_16x16x32_bf16(wah, etH[k2], a, 0, 0, 0);
                a = __builtin_amdgcn_mfma_f32_16x16x32_bf16(wal, etH[k2], a, 0, 0, 0);
                a = __builtin_amdgcn_mfma_f32_16x16x32_bf16(wah, etL[k2], a, 0, 0, 0);
            }
            // silu
            #pragma unroll
            for (int r = 0; r < 4; ++r) {
                float pre = a[r];
                hsi[half][r] = pre * __builtin_amdgcn_rcpf(1.f + __expf(-pre));
            }
        }
        // ---- pack layer-2 A-frag (lane-local by sigma construction): a[j]=h[ks*32+g*8+j]
        unsigned p0 = cvtpk(hsi[0][0], hsi[0][1]);
        unsigned p1 = cvtpk(hsi[0][2], hsi[0][3]);
        unsigned p2 = cvtpk(hsi[1][0], hsi[1][1]);
        unsigned p3 = cvtpk(hsi[1][2], hsi[1][3]);
        short8 ah = mk8(p0, p1, p2, p3);
        float q0 = hsi[0][0] - lowf(p0), q1 = hsi[0][1] - highf(p0);
        float q2 = hsi[0][2] - lowf(p1), q3 = hsi[0][3] - highf(p1);
        float q4 = hsi[1][0] - lowf(p2), q5 = hsi[1][1] - highf(p2);
        float q6 = hsi[1][2] - lowf(p3), q7 = hsi[1][3] - highf(p3);
        short8 al = mk8(cvtpk(q0, q1), cvtpk(q2, q3), cvtpk(q4, q5), cvtpk(q6, q7));

        // ---- layer 2: 6 c-tiles for this k-step ----
        #pragma unroll
        for (int nt = 0; nt < 6; ++nt) {
            int idx = ((ks * 6 + nt) * 64 + lane) * 8;
            short8 bh = *(const short8*)(w2h + idx);
            short8 bl = *(const short8*)(w2l + idx);
            acc2[nt] = __builtin_amdgcn_mfma_f32_16x16x32_bf16(ah, bh, acc2[nt], 0, 0, 0);
            acc2[nt] = __builtin_amdgcn_mfma_f32_16x16x32_bf16(ah, bl, acc2[nt], 0, 0, 0);
            acc2[nt] = __builtin_amdgcn_mfma_f32_16x16x32_bf16(al, bh, acc2[nt], 0, 0, 0);
        }
    }

    // ---- write w_sorted[slot][c]: lane holds edges g*4+r, channels nt*16+e15 ----
    #pragma unroll
    for (int nt = 0; nt < 6; ++nt) {
        #pragma unroll
        for (int r = 0; r < 4; ++r) {
            w_sorted[(slot0 + g * 4 + r) * 96 + nt * 16 + e15] = acc2[nt][r];
        }
    }
}

// ---------------- kernel B: per-node TP, LDS-staged w, no atomics ----------------
__global__ __launch_bounds__(576) void k_tp_node(
    const int* __restrict__ ssrc, const float* __restrict__ nemb,
    const float* __restrict__ w_sorted, const unsigned* __restrict__ rowp,
    float* __restrict__ out)
{
    __shared__ __align__(16) float sw[64 * 100];   // 25.6 KB, stride 100 (16B-aligned rows)
    __shared__ float gsm[2][9][65];                // stride-65: distinct banks per gi

    const int t = threadIdx.x;                     // 0..575 = (b,c)
    const int n = blockIdx.x;
    const int r0 = (int)rowp[n], r1 = (int)rowp[n + 1];

    const int b = (t >= NCH) ? 1 : 0;
    const int c = t - b * NCH;
    unsigned wi, gi;
    if (c < 32)       { wi = c;                          gi = 0; }
    else if (c < 128) { unsigned q = c - 32;  wi = 32 + q / 3u; gi = 1 + q % 3u; }
    else              { unsigned q = c - 128; wi = 64 + q / 5u; gi = 4 + q % 5u; }

    float acc = 0.f;
    for (int base = r0; base < r1; base += 64) {
        int cnt = min(64, r1 - base);
        __syncthreads();                            // protect prev-iteration reads
        // ---- stage w rows (coalesced float4 burst, all threads) ----
        for (int i = t; i < cnt * 24; i += 576) {
            int row = i / 24, c4 = i % 24;
            float4 v = *(const float4*)(w_sorted + (size_t)(base + row) * 96 + c4 * 4);
            *(float4*)&sw[row * 100 + c4 * 4] = v;
        }
        // ---- geometry (threads 0..127, runs concurrent with staging) ----
        if (t < 128) {
            int j = t >> 1, bb = t & 1;
            if (j < cnt) {
                int sn = ssrc[base + j];
                const float* xp = nemb + ((size_t)bb * NN + sn) * 3;
                const float* yp = nemb + ((size_t)bb * NN + n) * 3;
                float x0 = xp[0], x1 = xp[1], x2 = xp[2];
                float y0 = yp[0], y1 = yp[1], y2 = yp[2];
                const float inv3 = 0.5773502691896258f;
                const float inv2 = 0.7071067811865476f;
                const float inv6 = 0.4082482904638630f;
                gsm[bb][0][j] = (x0*y0 + x1*y1 + x2*y2) * inv3;
                gsm[bb][1][j] = (x1*y2 - x2*y1) * inv2;
                gsm[bb][2][j] = (x2*y0 - x0*y2) * inv2;
                gsm[bb][3][j] = (x0*y1 - x1*y0) * inv2;
                gsm[bb][4][j] = (x0*y1 + x1*y0) * inv2;
                gsm[bb][5][j] = (x1*y2 + x2*y1) * inv2;
                gsm[bb][6][j] = (x0*y2 + x2*y0) * inv2;
                gsm[bb][7][j] = (x0*y0 - x1*y1) * inv2;
                gsm[bb][8][j] = (2.0f*x2*y2 - x0*y0 - x1*y1) * inv6;
            }
        }
        __syncthreads();
        #pragma unroll 4
        for (int j = 0; j < cnt; ++j)
            acc = fmaf(sw[j * 100 + wi], gsm[b][gi][j], acc);
    }
    out[((size_t)b * NN + n) * NCH + c] = acc;     // coalesced; every element written
}

// ---------------- fused fallback (round-7 kernel; classic W1 frags) ----------------
struct SMemF {
    union {
        struct __align__(16) {
            unsigned short a2h[EPB * 64];
            unsigned short a2l[EPB * 64];
        };
        float sw[96 * 36];
    };
};

template <bool SORTED>
__global__ __launch_bounds__(256) void conv_fused_fb(
    const int* __restrict__ esrc, const int* __restrict__ edst,
    const float* __restrict__ nemb, const float* __restrict__ etype,
    const unsigned short* __restrict__ w1h, const unsigned short* __restrict__ w1l,
    const unsigned short* __restrict__ w2h, const unsigned short* __restrict__ w2l,
    const unsigned* __restrict__ perm,
    float* __restrict__ out)
{
    __shared__ SMemF U;
    __shared__ __align__(16) float geom_t[2][9][EPB];
    __shared__ int s_eidx[EPB], s_dst[EPB];
    __shared__ unsigned s_mask;

    const int t = threadIdx.x;
    const int lane = t & 63, w = t >> 6;
    const int g = lane >> 4, ln15 = lane & 15;
    const size_t slot0 = (size_t)blockIdx.x * EPB;

    if (t < EPB) {
        int e = SORTED ? (int)perm[slot0 + t] : (int)(slot0 + t);
        s_eidx[t] = e;
        s_dst[t] = edst[e];
    }
    __syncthreads();

    short8 etH[2][2], etL[2][2];
    #pragma unroll
    for (int k2 = 0; k2 < 2; ++k2) {
        #pragma unroll
        for (int m = 0; m < 2; ++m) {
            const float* rowp2 = etype + (size_t)s_eidx[m * 16 + ln15] * 64 + k2 * 32 + g * 8;
            float4 v0 = *(const float4*)rowp2;
            float4 v1 = *(const float4*)(rowp2 + 4);
            unsigned h0 = cvtpk(v0.x, v0.y), h1 = cvtpk(v0.z, v0.w);
            unsigned h2 = cvtpk(v1.x, v1.y), h3 = cvtpk(v1.z, v1.w);
            float l0 = v0.x - lowf(h0), l1 = v0.y - highf(h0);
            float l2 = v0.z - lowf(h1), l3 = v0.w - highf(h1);
            float l4 = v1.x - lowf(h2), l5 = v1.y - highf(h2);
            float l6 = v1.z - lowf(h3), l7 = v1.w - highf(h3);
            etH[k2][m] = mk8(h0, h1, h2, h3);
            etL[k2][m] = mk8(cvtpk(l0, l1), cvtpk(l2, l3), cvtpk(l4, l5), cvtpk(l6, l7));
        }
    }

    if (t < EPB * 2) {
        int e = t >> 1, b = t & 1;
        int sn = esrc[s_eidx[e]], dn = s_dst[e];
        const float* xp = nemb + ((size_t)b * NN + sn) * 3;
        const float* yp = nemb + ((size_t)b * NN + dn) * 3;
        float x0 = xp[0], x1 = xp[1], x2 = xp[2];
        float y0 = yp[0], y1 = yp[1], y2 = yp[2];
        const float inv3 = 0.5773502691896258f;
        const float inv2 = 0.7071067811865476f;
        const float inv6 = 0.4082482904638630f;
        geom_t[b][0][e] = (x0*y0 + x1*y1 + x2*y2) * inv3;
        geom_t[b][1][e] = (x1*y2 - x2*y1) * inv2;
        geom_t[b][2][e] = (x2*y0 - x0*y2) * inv2;
        geom_t[b][3][e] = (x0*y1 - x1*y0) * inv2;
        geom_t[b][4][e] = (x0*y1 + x1*y0) * inv2;
        geom_t[b][5][e] = (x1*y2 + x2*y1) * inv2;
        geom_t[b][6][e] = (x0*y2 + x2*y0) * inv2;
        geom_t[b][7][e] = (x0*y0 - x1*y1) * inv2;
        geom_t[b][8][e] = (2.0f*x2*y2 - x0*y0 - x1*y1) * inv6;
    } else if (t < 128) {
        int l = t - 64, e = l & 31;
        bool flag = (e > 0) && (s_dst[e] != s_dst[e - 1]);
        unsigned long long bal = __ballot(flag);
        if (l == 0) s_mask = (unsigned)bal;
    }

    const int m2 = w >> 1, nb = 3 * (w & 1);
    f32x4 acc2[3];
    #pragma unroll
    for (int n = 0; n < 3; ++n)
        #pragma unroll
        for (int r = 0; r < 4; ++r) acc2[n][r] = 0.f;

    #pragma unroll
    for (int qt = 0; qt < 4; ++qt) {
        f32x4 acc1[2];
        #pragma unroll
        for (int m = 0; m < 2; ++m)
            #pragma unroll
            for (int r = 0; r < 4; ++r) acc1[m][r] = 0.f;

        #pragma unroll
        for (int k2 = 0; k2 < 2; ++k2) {
            int idx = ((k2 * 16 + 4 * qt + w) * 64 + lane) * 8;
            short8 wah = *(const short8*)(w1h + idx);
            short8 wal = *(const short8*)(w1l + idx);
            #pragma unroll
            for (int m = 0; m < 2; ++m) {
                acc1[m] = __builtin_amdgcn_mfma_f32_16x16x32_bf16(wah, etH[k2][m], acc1[m], 0, 0, 0);
                acc1[m] = __builtin_amdgcn_mfma_f32_16x16x32_bf16(wal, etH[k2][m], acc1[m], 0, 0, 0);
                acc1[m] = __builtin_amdgcn_mfma_f32_16x16x32_bf16(wah, etL[k2][m], acc1[m], 0, 0, 0);
            }
        }

        #pragma unroll
        for (int m = 0; m < 2; ++m) {
            float p0 = acc1[m][0], p1 = acc1[m][1], p2 = acc1[m][2], p3 = acc1[m][3];
            float s0 = p0 * __builtin_amdgcn_rcpf(1.f + __expf(-p0));
            float s1 = p1 * __builtin_amdgcn_rcpf(1.f + __expf(-p1));
            float s2 = p2 * __builtin_amdgcn_rcpf(1.f + __expf(-p2));
            float s3 = p3 * __builtin_amdgcn_rcpf(1.f + __expf(-p3));
            unsigned hp0 = cvtpk(s0, s1), hp1 = cvtpk(s2, s3);
            float lo0 = s0 - lowf(hp0), lo1 = s1 - highf(hp0);
            float lo2 = s2 - lowf(hp1), lo3 = s3 - highf(hp1);
            unsigned lp0 = cvtpk(lo0, lo1), lp1 = cvtpk(lo2, lo3);
            int e = m * 16 + ln15;
            int boff = e * 128 + ((w * 32 + g * 8) ^ ((ln15 & 7) << 4));
            *(uint2*)((char*)U.a2h + boff) = make_uint2(hp0, hp1);
            *(uint2*)((char*)U.a2l + boff) = make_uint2(lp0, lp1);
        }
        __syncthreads();

        #pragma unroll
        for (int kk = 0; kk < 2; ++kk) {
            int kg = 2 * qt + kk;
            short8 bh[3], bl[3];
            #pragma unroll
            for (int n = 0; n < 3; ++n) {
                int idx = ((kg * 6 + nb + n) * 64 + lane) * 8;
                bh[n] = *(const short8*)(w2h + idx);
                bl[n] = *(const short8*)(w2l + idx);
            }
            int row = m2 * 16 + ln15;
            int boff = row * 128 + ((kk * 64 + g * 16) ^ ((ln15 & 7) << 4));
            short8 ah = *(const short8*)((const char*)U.a2h + boff);
            short8 al = *(const short8*)((const char*)U.a2l + boff);
            #pragma unroll
            for (int n = 0; n < 3; ++n) {
                acc2[n] = __builtin_amdgcn_mfma_f32_16x16x32_bf16(ah, bh[n], acc2[n], 0, 0, 0);
                acc2[n] = __builtin_amdgcn_mfma_f32_16x16x32_bf16(ah, bl[n], acc2[n], 0, 0, 0);
                acc2[n] = __builtin_amdgcn_mfma_f32_16x16x32_bf16(al, bh[n], acc2[n], 0, 0, 0);
            }
        }
        __syncthreads();
    }

    #pragma unroll
    for (int n = 0; n < 3; ++n) {
        int c = (nb + n) * 16 + ln15;
        #pragma unroll
        for (int r = 0; r < 4; ++r) {
            int e = m2 * 16 + g * 4 + r;
            U.sw[c * 36 + e] = acc2[n][r];
        }
    }
    __syncthreads();

    {
        unsigned mask = __builtin_amdgcn_readfirstlane(s_mask);
        for (int idx = t; idx < NCH * 2; idx += 256) {
            int b = idx >= NCH;
            int c = idx - b * NCH;
            unsigned wi, gi;
            if (c < 32)       { wi = c;                          gi = 0; }
            else if (c < 128) { unsigned q = c - 32;  wi = 32 + q / 3u; gi = 1 + q % 3u; }
            else              { unsigned q = c - 128; wi = 64 + q / 5u; gi = 4 + q % 5u; }
            const f32x4* wvp = (const f32x4*)&U.sw[wi * 36];
            const f32x4* gp  = (const f32x4*)&geom_t[b][gi][0];
            float* base = out + (size_t)b * NN * NCH + c;
            float acc = 0.f;
            int rs = 0;
            #pragma unroll
            for (int q = 0; q < 8; ++q) {
                f32x4 wv = wvp[q];
                f32x4 gv = gp[q];
                #pragma unroll
                for (int j = 0; j < 4; ++j) {
                    int e = q * 4 + j;
                    if (e && (mask & (1u << e))) {
                        float* addr = base + (size_t)s_dst[e - 1] * NCH;
                        if (SORTED && rs > 0) *addr = acc;
                        else atomicAdd(addr, acc);
                        acc = 0.f; rs = e;
                    }
                    acc = fmaf(wv[j], gv[j], acc);
                }
            }
            atomicAdd(base + (size_t)s_dst[EPB - 1] * NCH, acc);
        }
    }
}

extern "C" void kernel_launch(void* const* d_in, const int* in_sizes, int n_in,
                              void* d_out, int out_size, void* d_ws, size_t ws_size,
                              hipStream_t stream) {
    const int*   esrc  = (const int*)d_in[0];
    const int*   edst  = (const int*)d_in[1];
    const float* nemb  = (const float*)d_in[2];
    const float* etype = (const float*)d_in[3];
    const float* W1    = (const float*)d_in[4];
    const float* W2    = (const float*)d_in[5];
    float* out = (float*)d_out;

    // frag area: w1h, w1l, w2h, w2l, w1hs, w1ls
    const size_t frag_elems = 2 * (size_t)W1FRAG + 2 * (size_t)W2FRAG + 2 * (size_t)W1FRAG;
    const size_t frag_bytes = frag_elems * sizeof(unsigned short);
    unsigned short* w1h  = (unsigned short*)d_ws;
    unsigned short* w1l  = w1h + W1FRAG;
    unsigned short* w2h  = w1l + W1FRAG;
    unsigned short* w2l  = w2h + W2FRAG;
    unsigned short* w1hs = w2l + W2FRAG;
    unsigned short* w1ls = w1hs + W1FRAG;

    size_t o_cnt  = frag_bytes;
    size_t o_cur  = o_cnt  + (size_t)NBIN_PAD * 4;
    size_t o_rowp = o_cur  + (size_t)NBIN_PAD * 4;
    size_t o_perm = o_rowp + (size_t)NBIN_PAD * 4;    // rowp needs NN+1 <= NBIN_PAD
    size_t o_ssrc = o_perm + (size_t)EDGES * 4;
    size_t o_w    = (o_ssrc + (size_t)EDGES * 4 + 255) & ~(size_t)255;
    size_t need_split = o_w + (size_t)EDGES * 96 * 4;
    size_t need_sort  = o_perm + (size_t)EDGES * 4;

    k_wfrag<<<(int)((2 * W1FRAG + W2FRAG + 255) / 256), 256, 0, stream>>>(
        W1, W2, w1h, w1l, w2h, w2l, w1hs, w1ls);

    if (ws_size >= need_split) {
        unsigned* cnt  = (unsigned*)((char*)d_ws + o_cnt);
        unsigned* cur  = (unsigned*)((char*)d_ws + o_cur);
        unsigned* rowp = (unsigned*)((char*)d_ws + o_rowp);
        unsigned* perm = (unsigned*)((char*)d_ws + o_perm);
        int* ssrc      = (int*)((char*)d_ws + o_ssrc);
        float* w_sorted = (float*)((char*)d_ws + o_w);

        hipMemsetAsync(cnt, 0, (size_t)NBIN_PAD * 4, stream);
        k_hist<<<(EDGES + 255) / 256, 256, 0, stream>>>(edst, cnt);
        k_scan<<<1, 1024, 0, stream>>>(cnt, cur, rowp);
        k_perm2<<<(EDGES + 255) / 256, 256, 0, stream>>>(edst, esrc, cur, perm, ssrc);
        k_mlp<<<EDGES / EPA, 256, 0, stream>>>(etype, w1hs, w1ls, w2h, w2l, perm, w_sorted);
        k_tp_node<<<NN, 576, 0, stream>>>(ssrc, nemb, w_sorted, rowp, out);
        // no out-memset needed: k_tp_node writes every output element
    } else if (ws_size >= need_sort) {
        unsigned* cnt  = (unsigned*)((char*)d_ws + o_cnt);
        unsigned* cur  = (unsigned*)((char*)d_ws + o_cur);
        unsigned* rowp = (unsigned*)((char*)d_ws + o_rowp);
        unsigned* perm = (unsigned*)((char*)d_ws + o_perm);
        hipMemsetAsync(out, 0, (size_t)out_size * sizeof(float), stream);
        hipMemsetAsync(cnt, 0, (size_t)NBIN_PAD * 4, stream);
        k_hist<<<(EDGES + 255) / 256, 256, 0, stream>>>(edst, cnt);
        k_scan<<<1, 1024, 0, stream>>>(cnt, cur, rowp);
        k_perm<<<(EDGES + 255) / 256, 256, 0, stream>>>(edst, cur, perm);
        conv_fused_fb<true><<<EDGES / EPB, 256, 0, stream>>>(
            esrc, edst, nemb, etype, w1h, w1l, w2h, w2l, perm, out);
    } else {
        hipMemsetAsync(out, 0, (size_t)out_size * sizeof(float), stream);
        conv_fused_fb<false><<<EDGES / EPB, 256, 0, stream>>>(
            esrc, edst, nemb, etype, w1h, w1l, w2h, w2l, nullptr, out);
    }
}

// Round 12
// 216.568 us; speedup vs baseline: 1.6574x; 1.6574x over previous
//
#include <hip/hip_runtime.h>

#define EDGES 400000
#define NN 25000
#define NCH 288
#define EPA 64          // edges per block
#define NBIN_PAD 25024
#define SWS 68          // sw row stride in floats (17 float4, odd -> spread banks)

#define W1FRAG 16384   // 2 k2 * 16 nt * 64 lane * 8 el
#define W2FRAG 24576   // 8 k8 * 6 nt * 64 lane * 8 el

typedef float f32x4 __attribute__((ext_vector_type(4)));
typedef short short8 __attribute__((ext_vector_type(8)));

__device__ __forceinline__ unsigned short f2bf(float x) {          // RNE
    unsigned u = __float_as_uint(x);
    unsigned r = (u + 0x7fffu + ((u >> 16) & 1u)) >> 16;
    return (unsigned short)r;
}
__device__ __forceinline__ unsigned short f2bf_t(float x) {        // truncate
    return (unsigned short)(__float_as_uint(x) >> 16);
}
__device__ __forceinline__ float bf2f(unsigned short h) {
    return __uint_as_float(((unsigned)h) << 16);
}
__device__ __forceinline__ unsigned cvtpk(float a, float b) {      // 2xf32 -> 2xbf16 RNE
    unsigned r;
    asm("v_cvt_pk_bf16_f32 %0, %1, %2" : "=v"(r) : "v"(a), "v"(b));
    return r;
}
__device__ __forceinline__ float lowf(unsigned u)  { return __uint_as_float(u << 16); }
__device__ __forceinline__ float highf(unsigned u) { return __uint_as_float(u & 0xffff0000u); }

// ---------------- weight -> fragment-order bf16 hi/lo precompute ----------------
__global__ void k_wfrag(const float* __restrict__ W1, const float* __restrict__ W2,
                        unsigned short* __restrict__ w1h, unsigned short* __restrict__ w1l,
                        unsigned short* __restrict__ w2h, unsigned short* __restrict__ w2l) {
    int i = blockIdx.x * 256 + threadIdx.x;
    if (i < W1FRAG) {
        int j = i & 7, l = (i >> 3) & 63, nt = (i >> 9) & 15, k2 = (i >> 13) & 1;
        int n = nt * 16 + (l & 15), k = k2 * 32 + ((l >> 4) * 8) + j;
        float v = W1[k * 256 + n] * 0.125f;              // fold 1/sqrt(64)
        unsigned short hb = f2bf(v);
        w1h[i] = hb; w1l[i] = f2bf_t(v - bf2f(hb));
    } else if (i < W1FRAG + W2FRAG) {
        int i2 = i - W1FRAG;
        int j = i2 & 7, l = (i2 >> 3) & 63, r = i2 >> 9;  // r in [0,48)
        int nt = r % 6, k8 = r / 6;
        int n = nt * 16 + (l & 15), k = k8 * 32 + ((l >> 4) * 8) + j;
        float v = W2[k * 96 + n] * 0.015625f;            // fold 1/sqrt(256)*1/sqrt(16)
        unsigned short hb = f2bf(v);
        w2h[i2] = hb; w2l[i2] = f2bf_t(v - bf2f(hb));
    }
}

// ---------------- counting sort (dst-ordered edges) ----------------
__global__ void k_hist(const int* __restrict__ edst, unsigned* __restrict__ cnt) {
    int i = blockIdx.x * 256 + threadIdx.x;
    if (i < EDGES) atomicAdd(&cnt[edst[i]], 1u);
}

__global__ __launch_bounds__(1024) void k_scan(const unsigned* __restrict__ cnt,
                                               unsigned* __restrict__ cur) {
    __shared__ unsigned s_wt[16];
    __shared__ unsigned s_carry;
    const int t = threadIdx.x, lane = t & 63, wid = t >> 6;
    if (t == 0) s_carry = 0u;
    __syncthreads();
    for (int base = 0; base < NN; base += 1024) {
        int i = base + t;
        unsigned v = (i < NN) ? cnt[i] : 0u;
        unsigned incl = v;
        #pragma unroll
        for (int d = 1; d < 64; d <<= 1) {
            unsigned u = __shfl_up(incl, d);
            if (lane >= d) incl += u;
        }
        if (lane == 63) s_wt[wid] = incl;
        __syncthreads();
        if (wid == 0 && lane < 16) {
            unsigned wincl = s_wt[lane];
            #pragma unroll
            for (int d = 1; d < 16; d <<= 1) {
                unsigned u = __shfl_up(wincl, d);
                if (lane >= d) wincl += u;
            }
            s_wt[lane] = wincl;
        }
        __syncthreads();
        unsigned waveoff = (wid > 0) ? s_wt[wid - 1] : 0u;
        unsigned carry = s_carry;
        if (i < NN) cur[i] = carry + waveoff + incl - v;
        __syncthreads();
        if (t == 1023) s_carry = carry + s_wt[15];
        __syncthreads();
    }
}

__global__ void k_perm(const int* __restrict__ edst, unsigned* __restrict__ cur,
                       unsigned* __restrict__ perm) {
    int i = blockIdx.x * 256 + threadIdx.x;
    if (i < EDGES) {
        unsigned p = atomicAdd(&cur[edst[i]], 1u);
        perm[p] = (unsigned)i;
    }
}

// ---------------- fused conv: quarter-pipeline MLP (round-10) + in-block TP ----------------
struct SMemU {
    union {
        struct __align__(16) {
            unsigned short a1h[EPA * 64];   // 8 KB  etype hi [e][k] swizzled
            unsigned short a1l[EPA * 64];   // 8 KB
            unsigned short a2h[EPA * 64];   // 8 KB  h quarter hi
            unsigned short a2l[EPA * 64];   // 8 KB
        };
        float sw[96 * SWS];                 // 26.1 KB  w[c][e], overlay after MFMA phases
    };
};

template <bool SORTED>
__global__ __launch_bounds__(256) void conv_fused(
    const int* __restrict__ esrc, const int* __restrict__ edst,
    const float* __restrict__ nemb, const float* __restrict__ etype,
    const unsigned short* __restrict__ w1h, const unsigned short* __restrict__ w1l,
    const unsigned short* __restrict__ w2h, const unsigned short* __restrict__ w2l,
    const unsigned* __restrict__ perm,
    float* __restrict__ out)
{
    __shared__ SMemU U;                               // 32 KB
    __shared__ __align__(16) float gsm[2][9][SWS];    // 4.9 KB  [b][gi][e]
    __shared__ int s_eidx[EPA], s_dst[EPA];
    __shared__ unsigned s_mlo, s_mhi;

    const int t = threadIdx.x;
    const int lane = t & 63, w = t >> 6;
    const int g = lane >> 4, ln15 = lane & 15;
    const size_t slot0 = (size_t)blockIdx.x * EPA;

    if (t < EPA) {
        int e = SORTED ? (int)perm[slot0 + t] : (int)(slot0 + t);
        s_eidx[t] = e;
        s_dst[t] = edst[e];
    }
    __syncthreads();

    // ---- phase 1: stage etype tile -> a1 (all threads); geom (t<128); mask (wave 2) ----
    #pragma unroll
    for (int i = 0; i < 4; ++i) {
        int f4 = t + 256 * i;                  // 0..1023
        int row = f4 >> 4, q = f4 & 15;
        const float4* src = (const float4*)(etype + (size_t)s_eidx[row] * 64);
        float4 v = src[q];
        unsigned hp01 = cvtpk(v.x, v.y), hp23 = cvtpk(v.z, v.w);
        float lo0 = v.x - lowf(hp01), lo1 = v.y - highf(hp01);
        float lo2 = v.z - lowf(hp23), lo3 = v.w - highf(hp23);
        unsigned lp01 = cvtpk(lo0, lo1), lp23 = cvtpk(lo2, lo3);
        int boff = row * 128 + ((q * 8) ^ ((row & 7) << 4));
        *(uint2*)((char*)U.a1h + boff) = make_uint2(hp01, hp23);
        *(uint2*)((char*)U.a1l + boff) = make_uint2(lp01, lp23);
    }
    if (t < EPA * 2) {
        int e = t >> 1, b = t & 1;
        int sn = esrc[s_eidx[e]], dn = s_dst[e];
        const float* xp = nemb + ((size_t)b * NN + sn) * 3;
        const float* yp = nemb + ((size_t)b * NN + dn) * 3;
        float x0 = xp[0], x1 = xp[1], x2 = xp[2];
        float y0 = yp[0], y1 = yp[1], y2 = yp[2];
        const float inv3 = 0.5773502691896258f;
        const float inv2 = 0.7071067811865476f;
        const float inv6 = 0.4082482904638630f;
        gsm[b][0][e] = (x0*y0 + x1*y1 + x2*y2) * inv3;
        gsm[b][1][e] = (x1*y2 - x2*y1) * inv2;
        gsm[b][2][e] = (x2*y0 - x0*y2) * inv2;
        gsm[b][3][e] = (x0*y1 - x1*y0) * inv2;
        gsm[b][4][e] = (x0*y1 + x1*y0) * inv2;
        gsm[b][5][e] = (x1*y2 + x2*y1) * inv2;
        gsm[b][6][e] = (x0*y2 + x2*y0) * inv2;
        gsm[b][7][e] = (x0*y0 - x1*y1) * inv2;
        gsm[b][8][e] = (2.0f*x2*y2 - x0*y0 - x1*y1) * inv6;
    } else if (t < 192) {
        int e = t - 128;                                    // wave 2, lane = slot
        bool flag = (e > 0) && (s_dst[e] != s_dst[e - 1]);
        unsigned long long bal = __ballot(flag);
        if (e == 0) { s_mlo = (unsigned)bal; s_mhi = (unsigned)(bal >> 32); }
    }
    __syncthreads();

    // ---- MLP quarter pipeline (round-10 verbatim) ----
    const int mh = w & 1, nb = 3 * (w >> 1);
    f32x4 acc2[2][3];
    #pragma unroll
    for (int mm = 0; mm < 2; ++mm)
        #pragma unroll
        for (int n = 0; n < 3; ++n)
            #pragma unroll
            for (int r = 0; r < 4; ++r) acc2[mm][n][r] = 0.f;

    #pragma unroll
    for (int qt = 0; qt < 4; ++qt) {
        f32x4 acc1[4];
        #pragma unroll
        for (int m = 0; m < 4; ++m)
            #pragma unroll
            for (int r = 0; r < 4; ++r) acc1[m][r] = 0.f;

        #pragma unroll
        for (int k2 = 0; k2 < 2; ++k2) {
            int idx = ((k2 * 16 + 4 * qt + w) * 64 + lane) * 8;
            short8 wah = *(const short8*)(w1h + idx);
            short8 wal = *(const short8*)(w1l + idx);
            #pragma unroll
            for (int m = 0; m < 4; ++m) {
                int row = m * 16 + ln15;
                int boff = row * 128 + (((k2 * 64) + g * 16) ^ ((row & 7) << 4));
                short8 eth = *(const short8*)((const char*)U.a1h + boff);
                short8 etl = *(const short8*)((const char*)U.a1l + boff);
                acc1[m] = __builtin_amdgcn_mfma_f32_16x16x32_bf16(wah, eth, acc1[m], 0, 0, 0);
                acc1[m] = __builtin_amdgcn_mfma_f32_16x16x32_bf16(wal, eth, acc1[m], 0, 0, 0);
                acc1[m] = __builtin_amdgcn_mfma_f32_16x16x32_bf16(wah, etl, acc1[m], 0, 0, 0);
            }
        }

        #pragma unroll
        for (int m = 0; m < 4; ++m) {
            float p0 = acc1[m][0], p1 = acc1[m][1], p2 = acc1[m][2], p3 = acc1[m][3];
            float s0 = p0 * __builtin_amdgcn_rcpf(1.f + __expf(-p0));
            float s1 = p1 * __builtin_amdgcn_rcpf(1.f + __expf(-p1));
            float s2 = p2 * __builtin_amdgcn_rcpf(1.f + __expf(-p2));
            float s3 = p3 * __builtin_amdgcn_rcpf(1.f + __expf(-p3));
            unsigned hp0 = cvtpk(s0, s1), hp1 = cvtpk(s2, s3);
            float lo0 = s0 - lowf(hp0), lo1 = s1 - highf(hp0);
            float lo2 = s2 - lowf(hp1), lo3 = s3 - highf(hp1);
            unsigned lp0 = cvtpk(lo0, lo1), lp1 = cvtpk(lo2, lo3);
            int e = m * 16 + ln15;
            int boff = e * 128 + ((w * 32 + g * 8) ^ ((ln15 & 7) << 4));
            *(uint2*)((char*)U.a2h + boff) = make_uint2(hp0, hp1);
            *(uint2*)((char*)U.a2l + boff) = make_uint2(lp0, lp1);
        }
        __syncthreads();

        #pragma unroll
        for (int kk = 0; kk < 2; ++kk) {
            int kg = 2 * qt + kk;
            short8 bh[3], bl[3];
            #pragma unroll
            for (int n = 0; n < 3; ++n) {
                int idx = ((kg * 6 + nb + n) * 64 + lane) * 8;
                bh[n] = *(const short8*)(w2h + idx);
                bl[n] = *(const short8*)(w2l + idx);
            }
            #pragma unroll
            for (int mm = 0; mm < 2; ++mm) {
                int row = (2 * mh + mm) * 16 + ln15;
                int boff = row * 128 + ((kk * 64 + g * 16) ^ ((ln15 & 7) << 4));
                short8 ah = *(const short8*)((const char*)U.a2h + boff);
                short8 al = *(const short8*)((const char*)U.a2l + boff);
                #pragma unroll
                for (int n = 0; n < 3; ++n) {
                    acc2[mm][n] = __builtin_amdgcn_mfma_f32_16x16x32_bf16(ah, bh[n], acc2[mm][n], 0, 0, 0);
                    acc2[mm][n] = __builtin_amdgcn_mfma_f32_16x16x32_bf16(ah, bl[n], acc2[mm][n], 0, 0, 0);
                    acc2[mm][n] = __builtin_amdgcn_mfma_f32_16x16x32_bf16(al, bh[n], acc2[mm][n], 0, 0, 0);
                }
            }
        }
        __syncthreads();   // a2 consumed; next quarter overwrites (and a1/a2 dead after qt=3)
    }

    // ---- write w -> sw[c][e] overlay (a1+a2 dead; loop-end barrier passed) ----
    #pragma unroll
    for (int mm = 0; mm < 2; ++mm) {
        #pragma unroll
        for (int n = 0; n < 3; ++n) {
            int c = (nb + n) * 16 + ln15;
            int e_base = (2 * mh + mm) * 16 + g * 4;         // f32x4 over r
            *(f32x4*)&U.sw[c * SWS + e_base] = acc2[mm][n];
        }
    }
    __syncthreads();

    // ---- TP + run-grouped scatter over the block's 64 sorted slots ----
    {
        unsigned mlo = __builtin_amdgcn_readfirstlane(s_mlo);
        unsigned mhi = __builtin_amdgcn_readfirstlane(s_mhi);
        for (int idx = t; idx < NCH * 2; idx += 256) {
            int b = idx >= NCH;
            int c = idx - b * NCH;
            unsigned wi, gi;
            if (c < 32)       { wi = c;                          gi = 0; }
            else if (c < 128) { unsigned q = c - 32;  wi = 32 + q / 3u; gi = 1 + q % 3u; }
            else              { unsigned q = c - 128; wi = 64 + q / 5u; gi = 4 + q % 5u; }
            float* base = out + (size_t)b * NN * NCH + c;
            float acc = 0.f;
            int rs = 0;
            #pragma unroll
            for (int q4 = 0; q4 < 16; ++q4) {
                f32x4 wv = *(const f32x4*)&U.sw[wi * SWS + q4 * 4];
                f32x4 gv = *(const f32x4*)&gsm[b][gi][q4 * 4];
                #pragma unroll
                for (int j = 0; j < 4; ++j) {
                    int e = q4 * 4 + j;
                    bool bnd = (e < 32) ? ((mlo >> e) & 1u) : ((mhi >> (e - 32)) & 1u);
                    if (e && bnd) {
                        float* addr = base + (size_t)s_dst[e - 1] * NCH;
                        if (SORTED && rs > 0) *addr = acc;     // interior run: exclusive owner
                        else atomicAdd(addr, acc);             // first run: may span prev block
                        acc = 0.f; rs = e;
                    }
                    acc = fmaf(wv[j], gv[j], acc);
                }
            }
            atomicAdd(base + (size_t)s_dst[EPA - 1] * NCH, acc);   // last run: boundary
        }
    }
}

extern "C" void kernel_launch(void* const* d_in, const int* in_sizes, int n_in,
                              void* d_out, int out_size, void* d_ws, size_t ws_size,
                              hipStream_t stream) {
    const int*   esrc  = (const int*)d_in[0];
    const int*   edst  = (const int*)d_in[1];
    const float* nemb  = (const float*)d_in[2];
    const float* etype = (const float*)d_in[3];
    const float* W1    = (const float*)d_in[4];
    const float* W2    = (const float*)d_in[5];
    float* out = (float*)d_out;

    hipMemsetAsync(out, 0, (size_t)out_size * sizeof(float), stream);

    const size_t frag_bytes = (size_t)(2 * W1FRAG + 2 * W2FRAG) * sizeof(unsigned short);
    unsigned short* w1h = (unsigned short*)d_ws;
    unsigned short* w1l = w1h + W1FRAG;
    unsigned short* w2h = w1l + W1FRAG;
    unsigned short* w2l = w2h + W2FRAG;

    size_t o_cnt  = frag_bytes;
    size_t o_cur  = o_cnt + (size_t)NBIN_PAD * 4;
    size_t o_perm = o_cur + (size_t)NBIN_PAD * 4;
    size_t need_sort = o_perm + (size_t)EDGES * 4;

    k_wfrag<<<(W1FRAG + W2FRAG + 255) / 256, 256, 0, stream>>>(W1, W2, w1h, w1l, w2h, w2l);

    if (ws_size >= need_sort) {
        unsigned* cnt  = (unsigned*)((char*)d_ws + o_cnt);
        unsigned* cur  = (unsigned*)((char*)d_ws + o_cur);
        unsigned* perm = (unsigned*)((char*)d_ws + o_perm);
        hipMemsetAsync(cnt, 0, (size_t)NBIN_PAD * 4, stream);
        k_hist<<<(EDGES + 255) / 256, 256, 0, stream>>>(edst, cnt);
        k_scan<<<1, 1024, 0, stream>>>(cnt, cur);
        k_perm<<<(EDGES + 255) / 256, 256, 0, stream>>>(edst, cur, perm);
        conv_fused<true><<<EDGES / EPA, 256, 0, stream>>>(
            esrc, edst, nemb, etype, w1h, w1l, w2h, w2l, perm, out);
    } else {
        conv_fused<false><<<EDGES / EPA, 256, 0, stream>>>(
            esrc, edst, nemb, etype, w1h, w1l, w2h, w2l, nullptr, out);
    }
}